// Round 3
// baseline (413.935 us; speedup 1.0000x reference)
//
#include <hip/hip_runtime.h>

typedef unsigned short ushort_t;
typedef __attribute__((ext_vector_type(8))) short short8;   // 8 x bf16 bits
typedef __attribute__((ext_vector_type(4))) float f32x4;

__device__ inline float b2f(ushort_t u) {
    unsigned int x = ((unsigned int)u) << 16;
    return __builtin_bit_cast(float, x);
}
__device__ inline ushort_t f2b(float f) {
    unsigned int x = __builtin_bit_cast(unsigned int, f);
    x += 0x7fffu + ((x >> 16) & 1u);   // RNE
    return (ushort_t)(x >> 16);
}

__device__ inline void gload16(const void* g, void* l) {
    __builtin_amdgcn_global_load_lds(
        (const __attribute__((address_space(1))) void*)g,
        (__attribute__((address_space(3))) void*)l, 16, 0, 0);
}

// ---------------- fp32 -> bf16 cast (8 elems/thread) ----------------
__global__ __launch_bounds__(256)
void cast_bf16(const float* __restrict__ src, ushort_t* __restrict__ dst) {
    size_t i = ((size_t)blockIdx.x * 256 + threadIdx.x) * 8;
    f32x4 a = *reinterpret_cast<const f32x4*>(src + i);
    f32x4 b = *reinterpret_cast<const f32x4*>(src + i + 4);
    short8 v;
#pragma unroll
    for (int j = 0; j < 4; ++j) { v[j] = (short)f2b(a[j]); v[4 + j] = (short)f2b(b[j]); }
    *reinterpret_cast<short8*>(dst + i) = v;
}

// ---------------- transpose: dst[C][R] = src[R][C], src fp32 or bf16, dst bf16 ----------------
template <typename ST>
__global__ __launch_bounds__(64)
void transp(const ST* __restrict__ src, ushort_t* __restrict__ dst, int R, int C) {
    src += (size_t)blockIdx.z * R * C;
    dst += (size_t)blockIdx.z * R * C;
    int r0 = blockIdx.x * 64 + ((threadIdx.x >> 3) << 3);
    int c0 = blockIdx.y * 64 + ((threadIdx.x & 7) << 3);
    ushort_t v[8][8];
#pragma unroll
    for (int i = 0; i < 8; ++i) {
        const ST* p = src + (size_t)(r0 + i) * C + c0;
        if constexpr (sizeof(ST) == 4) {
            f32x4 a = *reinterpret_cast<const f32x4*>(p);
            f32x4 b = *reinterpret_cast<const f32x4*>(p + 4);
#pragma unroll
            for (int j = 0; j < 4; ++j) { v[i][j] = f2b(a[j]); v[i][4 + j] = f2b(b[j]); }
        } else {
            short8 a = *reinterpret_cast<const short8*>(p);
#pragma unroll
            for (int j = 0; j < 8; ++j) v[i][j] = (ushort_t)a[j];
        }
    }
#pragma unroll
    for (int c = 0; c < 8; ++c) {
        short8 w;
#pragma unroll
        for (int i = 0; i < 8; ++i) w[i] = (short)v[i][c];
        *reinterpret_cast<short8*>(dst + (size_t)(c0 + c) * R + r0) = w;
    }
}

// ---------------- GEMM: C[M][N] = A[M][K] @ Bt[N][K]^T + bias ----------------
// 128x128 tile, BK=64, 4 waves (2x2), swizzled LDS (XOR chunk^(row&7)).
// BHTD: scatter bf16 to [B,H,T,D] (b=m>>11, t=m&2047, h=n>>7, d=n&127); else fp32 linear.
template <bool BHTD>
__global__ __launch_bounds__(256)
void gemm_bt(const ushort_t* __restrict__ A, const ushort_t* __restrict__ Bt,
             const float* __restrict__ bias, void* __restrict__ Cv,
             int M, int N, int K) {
    __shared__ __align__(16) ushort_t As[128 * 64];
    __shared__ __align__(16) ushort_t Bs[128 * 64];
    const int tid = threadIdx.x, lane = tid & 63, wid = tid >> 6;
    const int l15 = lane & 15, g = lane >> 4;
    const int wr = wid >> 1, wc = wid & 1;
    const int m0 = blockIdx.y * 128, n0 = blockIdx.x * 128;
    f32x4 acc[4][4] = {};
    for (int k0 = 0; k0 < K; k0 += 64) {
#pragma unroll
        for (int is = 0; is < 4; ++is) {
            int c = is * 256 + tid;
            int row = c >> 3, sub = c & 7;
            int ks = (sub ^ (row & 7)) << 3;   // pre-swizzled global source (involution)
            char* ldst = (char*)As + (size_t)(is * 256 + wid * 64) * 16;
            gload16(A + (size_t)(m0 + row) * K + k0 + ks, ldst);
            char* ldstB = (char*)Bs + (size_t)(is * 256 + wid * 64) * 16;
            gload16(Bt + (size_t)(n0 + row) * K + k0 + ks, ldstB);
        }
        __syncthreads();
#pragma unroll
        for (int kk = 0; kk < 2; ++kk) {
            short8 af[4], bf[4];
#pragma unroll
            for (int i = 0; i < 4; ++i) {
                int ra = wr * 64 + i * 16 + l15;
                af[i] = *reinterpret_cast<const short8*>(
                    (const char*)As + ra * 128 + (((4 * kk + g) ^ (ra & 7)) << 4));
                int rb = wc * 64 + i * 16 + l15;
                bf[i] = *reinterpret_cast<const short8*>(
                    (const char*)Bs + rb * 128 + (((4 * kk + g) ^ (rb & 7)) << 4));
            }
#pragma unroll
            for (int i = 0; i < 4; ++i)
#pragma unroll
                for (int j = 0; j < 4; ++j)
                    acc[i][j] = __builtin_amdgcn_mfma_f32_16x16x32_bf16(af[i], bf[j], acc[i][j], 0, 0, 0);
        }
        __syncthreads();
    }
#pragma unroll
    for (int j = 0; j < 4; ++j) {
        int n = n0 + wc * 64 + j * 16 + l15;
        float bj = bias[n];
#pragma unroll
        for (int i = 0; i < 4; ++i) {
            int mbase = m0 + wr * 64 + i * 16 + g * 4;
#pragma unroll
            for (int r = 0; r < 4; ++r) {
                int m = mbase + r;
                float v = acc[i][j][r] + bj;
                if (BHTD) {
                    size_t addr = ((size_t)((m >> 11) * 16 + (n >> 7)) * 2048 + (m & 2047)) * 128 + (n & 127);
                    ((ushort_t*)Cv)[addr] = f2b(v);
                } else {
                    ((float*)Cv)[(size_t)m * N + n] = v;
                }
            }
        }
    }
}

// ---------------- "RoPE" as in source: angle depends on HEAD index, not position ----------------
// ref: n = x.shape[1] = HEADS after (0,2,1,3) transpose -> cos/sin indexed by head h.
// In-place on [B,H,T,D] bf16. idx strides: b:2^22, h:2^18, t:2^7, d:1.
__global__ __launch_bounds__(256)
void rope(ushort_t* __restrict__ Q, ushort_t* __restrict__ K) {
    ushort_t* P = blockIdx.y ? K : Q;
    size_t idx = ((size_t)blockIdx.x * 256 + threadIdx.x) * 8;
    int d = (int)(idx & 127);
    int h = (int)((idx >> 18) & 15);
    short8 v = *reinterpret_cast<const short8*>(P + idx);
#pragma unroll
    for (int p = 0; p < 4; ++p) {
        int i = (d >> 1) + p;
        float inv = expf(-(float)i * (9.210340371976184f / 64.0f)); // 10000^(-2i/128)
        float ang = (float)h * inv;                                  // HEAD index (source quirk)
        float sn, cs;
        sincosf(ang, &sn, &cs);
        float e = b2f((ushort_t)v[2 * p]), o = b2f((ushort_t)v[2 * p + 1]);
        v[2 * p]     = (short)f2b(e * cs - o * sn);
        v[2 * p + 1] = (short)f2b(e * sn + o * cs);
    }
    *reinterpret_cast<short8*>(P + idx) = v;
}

// ---------------- flash attention ----------------
// grid (T/64, H, B); 4 waves x 16 q-rows. K[B,H,T,D], Vt[B,H,D,T]. Out [B*T][2048] bf16.
__global__ __launch_bounds__(256)
void fattn(const ushort_t* __restrict__ Q, const ushort_t* __restrict__ K,
           const ushort_t* __restrict__ Vt, ushort_t* __restrict__ O) {
    __shared__ __align__(16) ushort_t Ks[64 * 128];   // [kv][d] swizzled
    __shared__ __align__(16) ushort_t Vs[128 * 64];   // [d][kv] swizzled
    __shared__ __align__(16) ushort_t Ps[4][16 * 72]; // per-wave P, rows padded to 72
    const int tid = threadIdx.x, lane = tid & 63, wid = tid >> 6;
    const int l15 = lane & 15, g = lane >> 4;
    const int h = blockIdx.y, b = blockIdx.z;
    const size_t base = ((size_t)b * 16 + h) * (2048 * 128);
    const int q0 = blockIdx.x * 64 + wid * 16;
    short8 qf[4];
#pragma unroll
    for (int c = 0; c < 4; ++c)
        qf[c] = *reinterpret_cast<const short8*>(Q + base + (size_t)(q0 + l15) * 128 + c * 32 + g * 8);
    f32x4 oacc[8] = {};
    float m_r[4], l_r[4];
#pragma unroll
    for (int r = 0; r < 4; ++r) { m_r[r] = -__builtin_inff(); l_r[r] = 0.f; }
    const float sc = 0.08838834764831845f;  // 1/sqrt(128)

    for (int kv0 = 0; kv0 < 2048; kv0 += 64) {
#pragma unroll
        for (int is = 0; is < 4; ++is) {
            {   // K tile [64][128]: 16 chunks/row
                int c = is * 256 + tid;
                int row = c >> 4, sub = c & 15;
                int dsrc = (sub ^ (row & 7)) << 3;
                gload16(K + base + (size_t)(kv0 + row) * 128 + dsrc,
                        (char*)Ks + (size_t)(is * 256 + wid * 64) * 16);
            }
            {   // Vt tile [128][64]: 8 chunks/row
                int c = is * 256 + tid;
                int row = c >> 3, sub = c & 7;
                int tsrc = (sub ^ (row & 7)) << 3;
                gload16(Vt + base + (size_t)row * 2048 + kv0 + tsrc,
                        (char*)Vs + (size_t)(is * 256 + wid * 64) * 16);
            }
        }
        __syncthreads();
        // S = Q K^T
        f32x4 s[4] = {};
#pragma unroll
        for (int nt = 0; nt < 4; ++nt) {
            int kvr = nt * 16 + l15;
#pragma unroll
            for (int c = 0; c < 4; ++c) {
                short8 kf = *reinterpret_cast<const short8*>(
                    (const char*)Ks + kvr * 256 + (((4 * c + g) ^ (kvr & 7)) << 4));
                s[nt] = __builtin_amdgcn_mfma_f32_16x16x32_bf16(qf[c], kf, s[nt], 0, 0, 0);
            }
        }
#pragma unroll
        for (int nt = 0; nt < 4; ++nt) s[nt] *= sc;
        // online softmax (rows live at (lane>>4)*4 + r)
        float pm[4], fac[4], rs[4];
#pragma unroll
        for (int r = 0; r < 4; ++r) {
            float v = fmaxf(fmaxf(s[0][r], s[1][r]), fmaxf(s[2][r], s[3][r]));
#pragma unroll
            for (int off = 1; off < 16; off <<= 1) v = fmaxf(v, __shfl_xor(v, off, 64));
            pm[r] = v;
            float mn = fmaxf(m_r[r], pm[r]);
            fac[r] = __expf(m_r[r] - mn);
            m_r[r] = mn;
            rs[r] = 0.f;
        }
#pragma unroll
        for (int nt = 0; nt < 4; ++nt) {
#pragma unroll
            for (int r = 0; r < 4; ++r) {
                float p = __expf(s[nt][r] - m_r[r]);
                ushort_t pb = f2b(p);
                Ps[wid][(g * 4 + r) * 72 + nt * 16 + l15] = pb;
                rs[r] += b2f(pb);   // sum what PV actually uses
            }
        }
#pragma unroll
        for (int r = 0; r < 4; ++r) {
            float v = rs[r];
#pragma unroll
            for (int off = 1; off < 16; off <<= 1) v += __shfl_xor(v, off, 64);
            l_r[r] = l_r[r] * fac[r] + v;
        }
#pragma unroll
        for (int nt2 = 0; nt2 < 8; ++nt2)
#pragma unroll
            for (int r = 0; r < 4; ++r) oacc[nt2][r] *= fac[r];
        // O += P V
#pragma unroll
        for (int kt = 0; kt < 2; ++kt) {
            short8 pa = *reinterpret_cast<const short8*>(
                (const char*)Ps[wid] + l15 * 144 + kt * 64 + g * 16);
#pragma unroll
            for (int nt2 = 0; nt2 < 8; ++nt2) {
                int dr = nt2 * 16 + l15;
                short8 vb = *reinterpret_cast<const short8*>(
                    (const char*)Vs + dr * 128 + (((kt * 4 + g) ^ (dr & 7)) << 4));
                oacc[nt2] = __builtin_amdgcn_mfma_f32_16x16x32_bf16(pa, vb, oacc[nt2], 0, 0, 0);
            }
        }
        __syncthreads();
    }
    float inv[4];
#pragma unroll
    for (int r = 0; r < 4; ++r) inv[r] = 1.f / l_r[r];
#pragma unroll
    for (int nt2 = 0; nt2 < 8; ++nt2) {
#pragma unroll
        for (int r = 0; r < 4; ++r) {
            int t = q0 + g * 4 + r;
            size_t addr = ((size_t)b * 2048 + t) * 2048 + (size_t)h * 128 + nt2 * 16 + l15;
            O[addr] = f2b(oacc[nt2][r] * inv[r]);
        }
    }
}

extern "C" void kernel_launch(void* const* d_in, const int* in_sizes, int n_in,
                              void* d_out, int out_size, void* d_ws, size_t ws_size,
                              hipStream_t stream) {
    const float* x  = (const float*)d_in[0];
    const float* Wq = (const float*)d_in[1];
    const float* bq = (const float*)d_in[2];
    const float* Wk = (const float*)d_in[3];
    const float* bk = (const float*)d_in[4];
    const float* Wv = (const float*)d_in[5];
    const float* bv = (const float*)d_in[6];
    const float* Wo = (const float*)d_in[7];
    const float* bo = (const float*)d_in[8];
    float* out = (float*)d_out;
    ushort_t* ws  = (ushort_t*)d_ws;

    const size_t WSZ = 2048ull * 2048;          // weight elems (4.19M)
    const size_t TSZ = 2ull * 16 * 2048 * 128;  // tensor elems (8.39M)
    ushort_t* xb  = ws;            // bf16 x
    ushort_t* Wtq = xb + TSZ;
    ushort_t* Wtk = Wtq + WSZ;
    ushort_t* Wtv = Wtk + WSZ;
    ushort_t* Wto = Wtv + WSZ;
    ushort_t* Qb  = Wto + WSZ;
    ushort_t* Kb  = Qb + TSZ;
    ushort_t* Vtb = Kb + TSZ;
    ushort_t* Sb  = Vtb + TSZ;   // V (from gemm), then attention output

    cast_bf16<<<dim3(4096), 256, 0, stream>>>(x, xb);
    transp<float><<<dim3(32, 32, 1), 64, 0, stream>>>(Wq, Wtq, 2048, 2048);
    transp<float><<<dim3(32, 32, 1), 64, 0, stream>>>(Wk, Wtk, 2048, 2048);
    transp<float><<<dim3(32, 32, 1), 64, 0, stream>>>(Wv, Wtv, 2048, 2048);
    transp<float><<<dim3(32, 32, 1), 64, 0, stream>>>(Wo, Wto, 2048, 2048);

    gemm_bt<true><<<dim3(16, 32), 256, 0, stream>>>(xb, Wtq, bq, Qb, 4096, 2048, 2048);
    gemm_bt<true><<<dim3(16, 32), 256, 0, stream>>>(xb, Wtk, bk, Kb, 4096, 2048, 2048);
    gemm_bt<true><<<dim3(16, 32), 256, 0, stream>>>(xb, Wtv, bv, Sb, 4096, 2048, 2048);

    rope<<<dim3(4096, 2), 256, 0, stream>>>(Qb, Kb);
    transp<ushort_t><<<dim3(32, 2, 32), 64, 0, stream>>>(Sb, Vtb, 2048, 128);   // V -> [B,H,D,T]

    fattn<<<dim3(32, 16, 2), 256, 0, stream>>>(Qb, Kb, Vtb, Sb);

    gemm_bt<false><<<dim3(16, 32), 256, 0, stream>>>(Sb, Wto, bo, out, 4096, 2048, 2048);
}

// Round 4
// 384.144 us; speedup vs baseline: 1.0776x; 1.0776x over previous
//
#include <hip/hip_runtime.h>

typedef unsigned short ushort_t;
typedef __attribute__((ext_vector_type(8))) short short8;   // 8 x bf16 bits
typedef __attribute__((ext_vector_type(4))) float f32x4;

__device__ inline float b2f(ushort_t u) {
    unsigned int x = ((unsigned int)u) << 16;
    return __builtin_bit_cast(float, x);
}
__device__ inline ushort_t f2b(float f) {
    unsigned int x = __builtin_bit_cast(unsigned int, f);
    x += 0x7fffu + ((x >> 16) & 1u);   // RNE
    return (ushort_t)(x >> 16);
}

__device__ inline void gload16(const void* g, void* l) {
    __builtin_amdgcn_global_load_lds(
        (const __attribute__((address_space(1))) void*)g,
        (__attribute__((address_space(3))) void*)l, 16, 0, 0);
}

// ---------------- fp32 -> bf16 cast (8 elems/thread) ----------------
__global__ __launch_bounds__(256)
void cast_bf16(const float* __restrict__ src, ushort_t* __restrict__ dst) {
    size_t i = ((size_t)blockIdx.x * 256 + threadIdx.x) * 8;
    f32x4 a = *reinterpret_cast<const f32x4*>(src + i);
    f32x4 b = *reinterpret_cast<const f32x4*>(src + i + 4);
    short8 v;
#pragma unroll
    for (int j = 0; j < 4; ++j) { v[j] = (short)f2b(a[j]); v[4 + j] = (short)f2b(b[j]); }
    *reinterpret_cast<short8*>(dst + i) = v;
}

// ---------------- transpose: dst[C][R] = src[R][C], src fp32 or bf16, dst bf16 ----------------
template <typename ST>
__global__ __launch_bounds__(64)
void transp(const ST* __restrict__ src, ushort_t* __restrict__ dst, int R, int C) {
    src += (size_t)blockIdx.z * R * C;
    dst += (size_t)blockIdx.z * R * C;
    int r0 = blockIdx.x * 64 + ((threadIdx.x >> 3) << 3);
    int c0 = blockIdx.y * 64 + ((threadIdx.x & 7) << 3);
    ushort_t v[8][8];
#pragma unroll
    for (int i = 0; i < 8; ++i) {
        const ST* p = src + (size_t)(r0 + i) * C + c0;
        if constexpr (sizeof(ST) == 4) {
            f32x4 a = *reinterpret_cast<const f32x4*>(p);
            f32x4 b = *reinterpret_cast<const f32x4*>(p + 4);
#pragma unroll
            for (int j = 0; j < 4; ++j) { v[i][j] = f2b(a[j]); v[i][4 + j] = f2b(b[j]); }
        } else {
            short8 a = *reinterpret_cast<const short8*>(p);
#pragma unroll
            for (int j = 0; j < 8; ++j) v[i][j] = (ushort_t)a[j];
        }
    }
#pragma unroll
    for (int c = 0; c < 8; ++c) {
        short8 w;
#pragma unroll
        for (int i = 0; i < 8; ++i) w[i] = (short)v[i][c];
        *reinterpret_cast<short8*>(dst + (size_t)(c0 + c) * R + r0) = w;
    }
}

// ---------------- GEMM: C[M][N] = A[M][K] @ Bt[N][K]^T + bias ----------------
// 128x128 tile, BK=64, 4 waves (2x2), swizzled LDS (XOR chunk^(row&7)).
// BHTD: scatter bf16 to [B,H,T,D]; ROPE: apply head-indexed rotation in epilogue.
template <bool BHTD, bool ROPE>
__global__ __launch_bounds__(256)
void gemm_bt(const ushort_t* __restrict__ A, const ushort_t* __restrict__ Bt,
             const float* __restrict__ bias, void* __restrict__ Cv,
             int M, int N, int K) {
    __shared__ __align__(16) ushort_t As[128 * 64];
    __shared__ __align__(16) ushort_t Bs[128 * 64];
    const int tid = threadIdx.x, lane = tid & 63, wid = tid >> 6;
    const int l15 = lane & 15, g = lane >> 4;
    const int wr = wid >> 1, wc = wid & 1;
    const int m0 = blockIdx.y * 128, n0 = blockIdx.x * 128;
    f32x4 acc[4][4] = {};
    for (int k0 = 0; k0 < K; k0 += 64) {
#pragma unroll
        for (int is = 0; is < 4; ++is) {
            int c = is * 256 + tid;
            int row = c >> 3, sub = c & 7;
            int ks = (sub ^ (row & 7)) << 3;   // pre-swizzled global source (involution)
            char* ldst = (char*)As + (size_t)(is * 256 + wid * 64) * 16;
            gload16(A + (size_t)(m0 + row) * K + k0 + ks, ldst);
            char* ldstB = (char*)Bs + (size_t)(is * 256 + wid * 64) * 16;
            gload16(Bt + (size_t)(n0 + row) * K + k0 + ks, ldstB);
        }
        __syncthreads();
#pragma unroll
        for (int kk = 0; kk < 2; ++kk) {
            short8 af[4], bf[4];
#pragma unroll
            for (int i = 0; i < 4; ++i) {
                int ra = wr * 64 + i * 16 + l15;
                af[i] = *reinterpret_cast<const short8*>(
                    (const char*)As + ra * 128 + (((4 * kk + g) ^ (ra & 7)) << 4));
                int rb = wc * 64 + i * 16 + l15;
                bf[i] = *reinterpret_cast<const short8*>(
                    (const char*)Bs + rb * 128 + (((4 * kk + g) ^ (rb & 7)) << 4));
            }
#pragma unroll
            for (int i = 0; i < 4; ++i)
#pragma unroll
                for (int j = 0; j < 4; ++j)
                    acc[i][j] = __builtin_amdgcn_mfma_f32_16x16x32_bf16(af[i], bf[j], acc[i][j], 0, 0, 0);
        }
        __syncthreads();
    }
#pragma unroll
    for (int j = 0; j < 4; ++j) {
        int n = n0 + wc * 64 + j * 16 + l15;
        float bj = bias[n];
        float sn = 0.f, cs = 1.f, sgn = 0.f;
        if (ROPE) {
            int d = n & 127, h = (n >> 7) & 15;
            float inv = expf(-(float)(d >> 1) * (9.210340371976184f / 64.0f)); // 10000^(-2i/128)
            sincosf((float)h * inv, &sn, &cs);
            sgn = (d & 1) ? sn : -sn;
        }
#pragma unroll
        for (int i = 0; i < 4; ++i) {
            int mbase = m0 + wr * 64 + i * 16 + g * 4;
#pragma unroll
            for (int r = 0; r < 4; ++r) {
                int m = mbase + r;
                float v = acc[i][j][r] + bj;
                if (ROPE) {
                    float p = __shfl_xor(v, 1, 64);   // d-pair partner (adjacent lane)
                    v = fmaf(p, sgn, v * cs);         // even: v*cs - p*sn ; odd: v*cs + p*sn
                }
                if (BHTD) {
                    size_t addr = ((size_t)((m >> 11) * 16 + (n >> 7)) * 2048 + (m & 2047)) * 128 + (n & 127);
                    ((ushort_t*)Cv)[addr] = f2b(v);
                } else {
                    ((float*)Cv)[(size_t)m * N + n] = v;
                }
            }
        }
    }
}

// ---------------- flash attention (2-phase double-buffered K/V pipeline) ----------------
// grid (T/64, H, B); 4 waves x 16 q-rows. K[B,H,T,D], Vt[B,H,D,T]. Out [B*T][2048] bf16.
__global__ __launch_bounds__(256)
void fattn(const ushort_t* __restrict__ Q, const ushort_t* __restrict__ K,
           const ushort_t* __restrict__ Vt, ushort_t* __restrict__ O) {
    __shared__ __align__(16) ushort_t Ks[2][64 * 128];   // [kv][d] swizzled
    __shared__ __align__(16) ushort_t Vs[2][128 * 64];   // [d][kv] swizzled
    __shared__ __align__(16) ushort_t Ps[4][16 * 72];    // per-wave P, rows padded to 72
    const int tid = threadIdx.x, lane = tid & 63, wid = tid >> 6;
    const int l15 = lane & 15, g = lane >> 4;
    const int h = blockIdx.y, b = blockIdx.z;
    const size_t base = ((size_t)b * 16 + h) * (2048 * 128);
    const int q0 = blockIdx.x * 64 + wid * 16;
    short8 qf[4];
#pragma unroll
    for (int c = 0; c < 4; ++c)
        qf[c] = *reinterpret_cast<const short8*>(Q + base + (size_t)(q0 + l15) * 128 + c * 32 + g * 8);
    f32x4 oacc[8] = {};
    float m_r[4], l_r[4];
#pragma unroll
    for (int r = 0; r < 4; ++r) { m_r[r] = -__builtin_inff(); l_r[r] = 0.f; }
    const float sc = 0.08838834764831845f;  // 1/sqrt(128)

    auto stage = [&](int kv0, int bsel) {
#pragma unroll
        for (int is = 0; is < 4; ++is) {
            {   // K tile [64][128]: 16 chunks/row
                int c = is * 256 + tid;
                int row = c >> 4, sub = c & 15;
                int dsrc = (sub ^ (row & 7)) << 3;
                gload16(K + base + (size_t)(kv0 + row) * 128 + dsrc,
                        (char*)Ks[bsel] + (size_t)(is * 256 + wid * 64) * 16);
            }
            {   // Vt tile [128][64]: 8 chunks/row
                int c = is * 256 + tid;
                int row = c >> 3, sub = c & 7;
                int tsrc = (sub ^ (row & 7)) << 3;
                gload16(Vt + base + (size_t)row * 2048 + kv0 + tsrc,
                        (char*)Vs[bsel] + (size_t)(is * 256 + wid * 64) * 16);
            }
        }
    };

    stage(0, 0);
    asm volatile("s_waitcnt vmcnt(0)" ::: "memory");
    __builtin_amdgcn_s_barrier();

    for (int it = 0; it < 32; ++it) {
        const int cur = it & 1;
        if (it < 31) stage((it + 1) << 6, cur ^ 1);   // prefetch flies under compute
        // S = Q K^T
        f32x4 s[4] = {};
        __builtin_amdgcn_s_setprio(1);
#pragma unroll
        for (int nt = 0; nt < 4; ++nt) {
            int kvr = nt * 16 + l15;
#pragma unroll
            for (int c = 0; c < 4; ++c) {
                short8 kf = *reinterpret_cast<const short8*>(
                    (const char*)Ks[cur] + kvr * 256 + (((4 * c + g) ^ (kvr & 7)) << 4));
                s[nt] = __builtin_amdgcn_mfma_f32_16x16x32_bf16(qf[c], kf, s[nt], 0, 0, 0);
            }
        }
        __builtin_amdgcn_s_setprio(0);
#pragma unroll
        for (int nt = 0; nt < 4; ++nt) s[nt] *= sc;
        // online softmax (rows live at (lane>>4)*4 + r)
        float pm[4], fac[4], rs[4];
#pragma unroll
        for (int r = 0; r < 4; ++r) {
            float v = fmaxf(fmaxf(s[0][r], s[1][r]), fmaxf(s[2][r], s[3][r]));
#pragma unroll
            for (int off = 1; off < 16; off <<= 1) v = fmaxf(v, __shfl_xor(v, off, 64));
            pm[r] = v;
            float mn = fmaxf(m_r[r], pm[r]);
            fac[r] = __expf(m_r[r] - mn);
            m_r[r] = mn;
            rs[r] = 0.f;
        }
#pragma unroll
        for (int nt = 0; nt < 4; ++nt) {
#pragma unroll
            for (int r = 0; r < 4; ++r) {
                float p = __expf(s[nt][r] - m_r[r]);
                ushort_t pb = f2b(p);
                Ps[wid][(g * 4 + r) * 72 + nt * 16 + l15] = pb;
                rs[r] += b2f(pb);   // sum what PV actually uses
            }
        }
#pragma unroll
        for (int r = 0; r < 4; ++r) {
            float v = rs[r];
#pragma unroll
            for (int off = 1; off < 16; off <<= 1) v += __shfl_xor(v, off, 64);
            l_r[r] = l_r[r] * fac[r] + v;
        }
#pragma unroll
        for (int nt2 = 0; nt2 < 8; ++nt2)
#pragma unroll
            for (int r = 0; r < 4; ++r) oacc[nt2][r] *= fac[r];
        // O += P V
        __builtin_amdgcn_s_setprio(1);
#pragma unroll
        for (int kt = 0; kt < 2; ++kt) {
            short8 pa = *reinterpret_cast<const short8*>(
                (const char*)Ps[wid] + l15 * 144 + kt * 64 + g * 16);
#pragma unroll
            for (int nt2 = 0; nt2 < 8; ++nt2) {
                int dr = nt2 * 16 + l15;
                short8 vb = *reinterpret_cast<const short8*>(
                    (const char*)Vs[cur] + dr * 128 + (((kt * 4 + g) ^ (dr & 7)) << 4));
                oacc[nt2] = __builtin_amdgcn_mfma_f32_16x16x32_bf16(pa, vb, oacc[nt2], 0, 0, 0);
            }
        }
        __builtin_amdgcn_s_setprio(0);
        // end of iter: drain prefetch, then barrier (raw: no auto full-drain before compute)
        asm volatile("s_waitcnt vmcnt(0)" ::: "memory");
        __builtin_amdgcn_s_barrier();
    }
    float inv[4];
#pragma unroll
    for (int r = 0; r < 4; ++r) inv[r] = 1.f / l_r[r];
#pragma unroll
    for (int nt2 = 0; nt2 < 8; ++nt2) {
#pragma unroll
        for (int r = 0; r < 4; ++r) {
            int t = q0 + g * 4 + r;
            size_t addr = ((size_t)b * 2048 + t) * 2048 + (size_t)h * 128 + nt2 * 16 + l15;
            O[addr] = f2b(oacc[nt2][r] * inv[r]);
        }
    }
}

extern "C" void kernel_launch(void* const* d_in, const int* in_sizes, int n_in,
                              void* d_out, int out_size, void* d_ws, size_t ws_size,
                              hipStream_t stream) {
    const float* x  = (const float*)d_in[0];
    const float* Wq = (const float*)d_in[1];
    const float* bq = (const float*)d_in[2];
    const float* Wk = (const float*)d_in[3];
    const float* bk = (const float*)d_in[4];
    const float* Wv = (const float*)d_in[5];
    const float* bv = (const float*)d_in[6];
    const float* Wo = (const float*)d_in[7];
    const float* bo = (const float*)d_in[8];
    float* out = (float*)d_out;
    ushort_t* ws  = (ushort_t*)d_ws;

    const size_t WSZ = 2048ull * 2048;          // weight elems (4.19M)
    const size_t TSZ = 2ull * 16 * 2048 * 128;  // tensor elems (8.39M)
    ushort_t* xb  = ws;            // bf16 x
    ushort_t* Wtq = xb + TSZ;
    ushort_t* Wtk = Wtq + WSZ;
    ushort_t* Wtv = Wtk + WSZ;
    ushort_t* Wto = Wtv + WSZ;
    ushort_t* Qb  = Wto + WSZ;
    ushort_t* Kb  = Qb + TSZ;
    ushort_t* Vtb = Kb + TSZ;
    ushort_t* Sb  = Vtb + TSZ;   // V (from gemm), then attention output

    cast_bf16<<<dim3(4096), 256, 0, stream>>>(x, xb);
    transp<float><<<dim3(32, 32, 1), 64, 0, stream>>>(Wq, Wtq, 2048, 2048);
    transp<float><<<dim3(32, 32, 1), 64, 0, stream>>>(Wk, Wtk, 2048, 2048);
    transp<float><<<dim3(32, 32, 1), 64, 0, stream>>>(Wv, Wtv, 2048, 2048);
    transp<float><<<dim3(32, 32, 1), 64, 0, stream>>>(Wo, Wto, 2048, 2048);

    gemm_bt<true, true ><<<dim3(16, 32), 256, 0, stream>>>(xb, Wtq, bq, Qb, 4096, 2048, 2048);
    gemm_bt<true, true ><<<dim3(16, 32), 256, 0, stream>>>(xb, Wtk, bk, Kb, 4096, 2048, 2048);
    gemm_bt<true, false><<<dim3(16, 32), 256, 0, stream>>>(xb, Wtv, bv, Sb, 4096, 2048, 2048);

    transp<ushort_t><<<dim3(32, 2, 32), 64, 0, stream>>>(Sb, Vtb, 2048, 128);   // V -> [B,H,D,T]

    fattn<<<dim3(32, 16, 2), 256, 0, stream>>>(Qb, Kb, Vtb, Sb);

    gemm_bt<false, false><<<dim3(16, 32), 256, 0, stream>>>(Sb, Wto, bo, out, 4096, 2048, 2048);
}

// Round 5
// 374.872 us; speedup vs baseline: 1.1042x; 1.0247x over previous
//
#include <hip/hip_runtime.h>

typedef unsigned short ushort_t;
typedef unsigned int uint_t;
typedef __attribute__((ext_vector_type(8))) short short8;   // 8 x bf16 bits
typedef __attribute__((ext_vector_type(4))) float f32x4;
typedef __attribute__((ext_vector_type(4))) unsigned short ushort4_t;
typedef __attribute__((ext_vector_type(4))) unsigned int uint4_t;

__device__ inline float b2f(ushort_t u) {
    unsigned int x = ((unsigned int)u) << 16;
    return __builtin_bit_cast(float, x);
}
__device__ inline ushort_t f2b(float f) {
    unsigned int x = __builtin_bit_cast(unsigned int, f);
    x += 0x7fffu + ((x >> 16) & 1u);   // RNE
    return (ushort_t)(x >> 16);
}

__device__ inline void gload16(const void* g, void* l) {
    __builtin_amdgcn_global_load_lds(
        (const __attribute__((address_space(1))) void*)g,
        (__attribute__((address_space(3))) void*)l, 16, 0, 0);
}

// ---------------- fp32 -> bf16 cast (8 elems/thread) ----------------
__global__ __launch_bounds__(256)
void cast_bf16(const float* __restrict__ src, ushort_t* __restrict__ dst) {
    size_t i = ((size_t)blockIdx.x * 256 + threadIdx.x) * 8;
    f32x4 a = *reinterpret_cast<const f32x4*>(src + i);
    f32x4 b = *reinterpret_cast<const f32x4*>(src + i + 4);
    short8 v;
#pragma unroll
    for (int j = 0; j < 4; ++j) { v[j] = (short)f2b(a[j]); v[4 + j] = (short)f2b(b[j]); }
    *reinterpret_cast<short8*>(dst + i) = v;
}

// ---------------- transpose: dst[C][R] = src[R][C], src fp32 or bf16, dst bf16 ----------------
template <typename ST>
__global__ __launch_bounds__(64)
void transp(const ST* __restrict__ src, ushort_t* __restrict__ dst, int R, int C) {
    src += (size_t)blockIdx.z * R * C;
    dst += (size_t)blockIdx.z * R * C;
    int r0 = blockIdx.x * 64 + ((threadIdx.x >> 3) << 3);
    int c0 = blockIdx.y * 64 + ((threadIdx.x & 7) << 3);
    ushort_t v[8][8];
#pragma unroll
    for (int i = 0; i < 8; ++i) {
        const ST* p = src + (size_t)(r0 + i) * C + c0;
        if constexpr (sizeof(ST) == 4) {
            f32x4 a = *reinterpret_cast<const f32x4*>(p);
            f32x4 b = *reinterpret_cast<const f32x4*>(p + 4);
#pragma unroll
            for (int j = 0; j < 4; ++j) { v[i][j] = f2b(a[j]); v[i][4 + j] = f2b(b[j]); }
        } else {
            short8 a = *reinterpret_cast<const short8*>(p);
#pragma unroll
            for (int j = 0; j < 8; ++j) v[i][j] = (ushort_t)a[j];
        }
    }
#pragma unroll
    for (int c = 0; c < 8; ++c) {
        short8 w;
#pragma unroll
        for (int i = 0; i < 8; ++i) w[i] = (short)v[i][c];
        *reinterpret_cast<short8*>(dst + (size_t)(c0 + c) * R + r0) = w;
    }
}

// ---------------- GEMM: C[M][N] = A[M][K] @ Bt[N][K]^T + bias ----------------
// 128x128 tile, BK=64, 4 waves (2x2), swizzled LDS (XOR chunk^(row&7)).
// BHTD: scatter bf16 to [B,H,T,D]; ROPE: apply head-indexed rotation in epilogue.
template <bool BHTD, bool ROPE>
__global__ __launch_bounds__(256)
void gemm_bt(const ushort_t* __restrict__ A, const ushort_t* __restrict__ Bt,
             const float* __restrict__ bias, void* __restrict__ Cv,
             int M, int N, int K) {
    __shared__ __align__(16) ushort_t As[128 * 64];
    __shared__ __align__(16) ushort_t Bs[128 * 64];
    const int tid = threadIdx.x, lane = tid & 63, wid = tid >> 6;
    const int l15 = lane & 15, g = lane >> 4;
    const int wr = wid >> 1, wc = wid & 1;
    const int m0 = blockIdx.y * 128, n0 = blockIdx.x * 128;
    f32x4 acc[4][4] = {};
    for (int k0 = 0; k0 < K; k0 += 64) {
#pragma unroll
        for (int is = 0; is < 4; ++is) {
            int c = is * 256 + tid;
            int row = c >> 3, sub = c & 7;
            int ks = (sub ^ (row & 7)) << 3;   // pre-swizzled global source (involution)
            char* ldst = (char*)As + (size_t)(is * 256 + wid * 64) * 16;
            gload16(A + (size_t)(m0 + row) * K + k0 + ks, ldst);
            char* ldstB = (char*)Bs + (size_t)(is * 256 + wid * 64) * 16;
            gload16(Bt + (size_t)(n0 + row) * K + k0 + ks, ldstB);
        }
        __syncthreads();
#pragma unroll
        for (int kk = 0; kk < 2; ++kk) {
            short8 af[4], bf[4];
#pragma unroll
            for (int i = 0; i < 4; ++i) {
                int ra = wr * 64 + i * 16 + l15;
                af[i] = *reinterpret_cast<const short8*>(
                    (const char*)As + ra * 128 + (((4 * kk + g) ^ (ra & 7)) << 4));
                int rb = wc * 64 + i * 16 + l15;
                bf[i] = *reinterpret_cast<const short8*>(
                    (const char*)Bs + rb * 128 + (((4 * kk + g) ^ (rb & 7)) << 4));
            }
#pragma unroll
            for (int i = 0; i < 4; ++i)
#pragma unroll
                for (int j = 0; j < 4; ++j)
                    acc[i][j] = __builtin_amdgcn_mfma_f32_16x16x32_bf16(af[i], bf[j], acc[i][j], 0, 0, 0);
        }
        __syncthreads();
    }
#pragma unroll
    for (int j = 0; j < 4; ++j) {
        int n = n0 + wc * 64 + j * 16 + l15;
        float bj = bias[n];
        float sn = 0.f, cs = 1.f, sgn = 0.f;
        if (ROPE) {
            int d = n & 127, h = (n >> 7) & 15;
            float inv = expf(-(float)(d >> 1) * (9.210340371976184f / 64.0f)); // 10000^(-2i/128)
            sincosf((float)h * inv, &sn, &cs);
            sgn = (d & 1) ? sn : -sn;
        }
#pragma unroll
        for (int i = 0; i < 4; ++i) {
            int mbase = m0 + wr * 64 + i * 16 + g * 4;
#pragma unroll
            for (int r = 0; r < 4; ++r) {
                int m = mbase + r;
                float v = acc[i][j][r] + bj;
                if (ROPE) {
                    float p = __shfl_xor(v, 1, 64);   // d-pair partner (adjacent lane)
                    v = fmaf(p, sgn, v * cs);         // even: v*cs - p*sn ; odd: v*cs + p*sn
                }
                if (BHTD) {
                    size_t addr = ((size_t)((m >> 11) * 16 + (n >> 7)) * 2048 + (m & 2047)) * 128 + (n & 127);
                    ((ushort_t*)Cv)[addr] = f2b(v);
                } else {
                    ((float*)Cv)[(size_t)m * N + n] = v;
                }
            }
        }
    }
}

// ---------------- flash attention: swapped-QK^T, in-register softmax ----------------
// grid (T/64, H, B); 4 waves x 16 q-rows. K[B,H,T,D], Vt[B,H,D,T]. Out [B*T][2048] bf16.
// s[nt][r] = S[kv=16nt+4g+r][q=l15]; oacc[nt2][r] = O^T[d=16nt2+4g+r][q=l15].
__global__ __launch_bounds__(256)
void fattn(const ushort_t* __restrict__ Q, const ushort_t* __restrict__ K,
           const ushort_t* __restrict__ Vt, ushort_t* __restrict__ O) {
    __shared__ __align__(16) ushort_t Ks[2][64 * 128];   // [kv][d] swizzled
    __shared__ __align__(16) ushort_t Vs[2][128 * 64];   // [d][kv] swizzled
    const int tid = threadIdx.x, lane = tid & 63, wid = tid >> 6;
    const int l15 = lane & 15, g = lane >> 4;
    const int h = blockIdx.y, b = blockIdx.z;
    const size_t base = ((size_t)b * 16 + h) * (2048 * 128);
    const int q0 = blockIdx.x * 64 + wid * 16;
    short8 qf[4];
#pragma unroll
    for (int c = 0; c < 4; ++c)
        qf[c] = *reinterpret_cast<const short8*>(Q + base + (size_t)(q0 + l15) * 128 + c * 32 + g * 8);
    f32x4 oacc[8] = {};
    float m_r = -__builtin_inff(), l_r = 0.f;
    const float c2 = 0.12751744f;   // (1/sqrt(128)) * log2(e)
    // bpermute byte-addrs for P redistribution (iteration-invariant)
    const int addrA = ((32 * (g & 1)) + l15) << 2;
    const int addrB = addrA + 64;
    const bool hi = (lane & 32) != 0;

    auto stage = [&](int kv0, int bsel) {
#pragma unroll
        for (int is = 0; is < 4; ++is) {
            {   // K tile [64][128]: 16 chunks/row
                int c = is * 256 + tid;
                int row = c >> 4, sub = c & 15;
                int dsrc = (sub ^ (row & 7)) << 3;
                gload16(K + base + (size_t)(kv0 + row) * 128 + dsrc,
                        (char*)Ks[bsel] + (size_t)(is * 256 + wid * 64) * 16);
            }
            {   // Vt tile [128][64]: 8 chunks/row
                int c = is * 256 + tid;
                int row = c >> 3, sub = c & 7;
                int tsrc = (sub ^ (row & 7)) << 3;
                gload16(Vt + base + (size_t)row * 2048 + kv0 + tsrc,
                        (char*)Vs[bsel] + (size_t)(is * 256 + wid * 64) * 16);
            }
        }
    };

    stage(0, 0);
    asm volatile("s_waitcnt vmcnt(0)" ::: "memory");
    __builtin_amdgcn_s_barrier();

    for (int it = 0; it < 32; ++it) {
        const int cur = it & 1;
        if (it < 31) stage((it + 1) << 6, cur ^ 1);   // prefetch flies under compute
        // S^T = K Q^T
        f32x4 s[4] = {};
        __builtin_amdgcn_s_setprio(1);
#pragma unroll
        for (int nt = 0; nt < 4; ++nt) {
            int kvr = nt * 16 + l15;
#pragma unroll
            for (int c = 0; c < 4; ++c) {
                short8 kf = *reinterpret_cast<const short8*>(
                    (const char*)Ks[cur] + kvr * 256 + (((4 * c + g) ^ (kvr & 7)) << 4));
                s[nt] = __builtin_amdgcn_mfma_f32_16x16x32_bf16(kf, qf[c], s[nt], 0, 0, 0);
            }
        }
        __builtin_amdgcn_s_setprio(0);
        // row max: 15 in-reg + 2 shfl (q row spread over 4 g-lanes)
        float pm = fmaxf(fmaxf(fmaxf(s[0][0], s[0][1]), fmaxf(s[0][2], s[0][3])),
                         fmaxf(fmaxf(s[1][0], s[1][1]), fmaxf(s[1][2], s[1][3])));
        pm = fmaxf(pm, fmaxf(fmaxf(fmaxf(s[2][0], s[2][1]), fmaxf(s[2][2], s[2][3])),
                             fmaxf(fmaxf(s[3][0], s[3][1]), fmaxf(s[3][2], s[3][3]))));
        pm = fmaxf(pm, __shfl_xor(pm, 16, 64));
        pm = fmaxf(pm, __shfl_xor(pm, 32, 64));
        // defer-max (T13): rescale only when max grew past THR (raw-score units)
        if (!__all(pm <= m_r + 40.f)) {
            float mn = fmaxf(m_r, pm);
            float fac = exp2f(c2 * (m_r - mn));
            m_r = mn;
            l_r *= fac;
#pragma unroll
            for (int nt2 = 0; nt2 < 8; ++nt2)
#pragma unroll
                for (int r = 0; r < 4; ++r) oacc[nt2][r] *= fac;
        }
        // P = exp2(c2*(s-m)), pack to bf16 pair-words, accumulate row-sum
        uint_t W[4][2];
        float rs = 0.f;
#pragma unroll
        for (int nt = 0; nt < 4; ++nt) {
            float p0 = exp2f((s[nt][0] - m_r) * c2);
            float p1 = exp2f((s[nt][1] - m_r) * c2);
            float p2 = exp2f((s[nt][2] - m_r) * c2);
            float p3 = exp2f((s[nt][3] - m_r) * c2);
            rs += (p0 + p1) + (p2 + p3);
            W[nt][0] = (uint_t)f2b(p0) | ((uint_t)f2b(p1) << 16);
            W[nt][1] = (uint_t)f2b(p2) | ((uint_t)f2b(p3) << 16);
        }
        rs += __shfl_xor(rs, 16, 64);
        rs += __shfl_xor(rs, 32, 64);
        l_r += rs;
        // O^T += V^T P : redistribute P words to B-fragment layout via bpermute
        __builtin_amdgcn_s_setprio(1);
#pragma unroll
        for (int ks = 0; ks < 2; ++ks) {
            uint_t xa, xb, w0, w1, w2, w3;
            xa = (uint_t)__builtin_amdgcn_ds_bpermute(addrA, (int)W[2 * ks][0]);
            xb = (uint_t)__builtin_amdgcn_ds_bpermute(addrA, (int)W[2 * ks + 1][0]);
            w0 = hi ? xb : xa;
            xa = (uint_t)__builtin_amdgcn_ds_bpermute(addrA, (int)W[2 * ks][1]);
            xb = (uint_t)__builtin_amdgcn_ds_bpermute(addrA, (int)W[2 * ks + 1][1]);
            w1 = hi ? xb : xa;
            xa = (uint_t)__builtin_amdgcn_ds_bpermute(addrB, (int)W[2 * ks][0]);
            xb = (uint_t)__builtin_amdgcn_ds_bpermute(addrB, (int)W[2 * ks + 1][0]);
            w2 = hi ? xb : xa;
            xa = (uint_t)__builtin_amdgcn_ds_bpermute(addrB, (int)W[2 * ks][1]);
            xb = (uint_t)__builtin_amdgcn_ds_bpermute(addrB, (int)W[2 * ks + 1][1]);
            w3 = hi ? xb : xa;
            uint4_t wv; wv[0] = w0; wv[1] = w1; wv[2] = w2; wv[3] = w3;
            short8 pb = __builtin_bit_cast(short8, wv);
#pragma unroll
            for (int nt2 = 0; nt2 < 8; ++nt2) {
                int dr = nt2 * 16 + l15;
                short8 vb = *reinterpret_cast<const short8*>(
                    (const char*)Vs[cur] + dr * 128 + (((ks * 4 + g) ^ (dr & 7)) << 4));
                oacc[nt2] = __builtin_amdgcn_mfma_f32_16x16x32_bf16(vb, pb, oacc[nt2], 0, 0, 0);
            }
        }
        __builtin_amdgcn_s_setprio(0);
        // end of iter: drain prefetch, then barrier
        asm volatile("s_waitcnt vmcnt(0)" ::: "memory");
        __builtin_amdgcn_s_barrier();
    }
    float inv = 1.f / l_r;
    const size_t orow = ((size_t)b * 2048 + q0 + l15) * 2048 + (size_t)h * 128;
#pragma unroll
    for (int nt2 = 0; nt2 < 8; ++nt2) {
        ushort4_t w;
#pragma unroll
        for (int r = 0; r < 4; ++r) w[r] = f2b(oacc[nt2][r] * inv);
        *reinterpret_cast<ushort4_t*>(O + orow + nt2 * 16 + g * 4) = w;
    }
}

extern "C" void kernel_launch(void* const* d_in, const int* in_sizes, int n_in,
                              void* d_out, int out_size, void* d_ws, size_t ws_size,
                              hipStream_t stream) {
    const float* x  = (const float*)d_in[0];
    const float* Wq = (const float*)d_in[1];
    const float* bq = (const float*)d_in[2];
    const float* Wk = (const float*)d_in[3];
    const float* bk = (const float*)d_in[4];
    const float* Wv = (const float*)d_in[5];
    const float* bv = (const float*)d_in[6];
    const float* Wo = (const float*)d_in[7];
    const float* bo = (const float*)d_in[8];
    float* out = (float*)d_out;
    ushort_t* ws  = (ushort_t*)d_ws;

    const size_t WSZ = 2048ull * 2048;          // weight elems (4.19M)
    const size_t TSZ = 2ull * 16 * 2048 * 128;  // tensor elems (8.39M)
    ushort_t* xb  = ws;            // bf16 x
    ushort_t* Wtq = xb + TSZ;
    ushort_t* Wtk = Wtq + WSZ;
    ushort_t* Wtv = Wtk + WSZ;
    ushort_t* Wto = Wtv + WSZ;
    ushort_t* Qb  = Wto + WSZ;
    ushort_t* Kb  = Qb + TSZ;
    ushort_t* Vtb = Kb + TSZ;
    ushort_t* Sb  = Vtb + TSZ;   // V (from gemm), then attention output

    cast_bf16<<<dim3(4096), 256, 0, stream>>>(x, xb);
    transp<float><<<dim3(32, 32, 1), 64, 0, stream>>>(Wq, Wtq, 2048, 2048);
    transp<float><<<dim3(32, 32, 1), 64, 0, stream>>>(Wk, Wtk, 2048, 2048);
    transp<float><<<dim3(32, 32, 1), 64, 0, stream>>>(Wv, Wtv, 2048, 2048);
    transp<float><<<dim3(32, 32, 1), 64, 0, stream>>>(Wo, Wto, 2048, 2048);

    gemm_bt<true, true ><<<dim3(16, 32), 256, 0, stream>>>(xb, Wtq, bq, Qb, 4096, 2048, 2048);
    gemm_bt<true, true ><<<dim3(16, 32), 256, 0, stream>>>(xb, Wtk, bk, Kb, 4096, 2048, 2048);
    gemm_bt<true, false><<<dim3(16, 32), 256, 0, stream>>>(xb, Wtv, bv, Sb, 4096, 2048, 2048);

    transp<ushort_t><<<dim3(32, 2, 32), 64, 0, stream>>>(Sb, Vtb, 2048, 128);   // V -> [B,H,D,T]

    fattn<<<dim3(32, 16, 2), 256, 0, stream>>>(Qb, Kb, Vtb, Sb);

    gemm_bt<false, false><<<dim3(16, 32), 256, 0, stream>>>(Sb, Wto, bo, out, 4096, 2048, 2048);
}

// Round 6
// 326.765 us; speedup vs baseline: 1.2668x; 1.1472x over previous
//
#include <hip/hip_runtime.h>

typedef unsigned short ushort_t;
typedef unsigned int uint_t;
typedef __attribute__((ext_vector_type(8))) short short8;   // 8 x bf16 bits
typedef __attribute__((ext_vector_type(4))) float f32x4;
typedef __attribute__((ext_vector_type(4))) unsigned short ushort4_t;
typedef __attribute__((ext_vector_type(4))) unsigned int uint4_t;

__device__ inline float b2f(ushort_t u) {
    unsigned int x = ((unsigned int)u) << 16;
    return __builtin_bit_cast(float, x);
}
__device__ inline ushort_t f2b(float f) {
    unsigned int x = __builtin_bit_cast(unsigned int, f);
    x += 0x7fffu + ((x >> 16) & 1u);   // RNE
    return (ushort_t)(x >> 16);
}
__device__ inline uint_t cvt_pk_bf16(float lo, float hi) {
    uint_t r;
    asm("v_cvt_pk_bf16_f32 %0, %1, %2" : "=v"(r) : "v"(lo), "v"(hi));
    return r;   // low16 = bf16(lo), high16 = bf16(hi)
}

__device__ inline void gload16(const void* g, void* l) {
    __builtin_amdgcn_global_load_lds(
        (const __attribute__((address_space(1))) void*)g,
        (__attribute__((address_space(3))) void*)l, 16, 0, 0);
}

// ---------------- fp32 -> bf16 cast (8 elems/thread) ----------------
__global__ __launch_bounds__(256)
void cast_bf16(const float* __restrict__ src, ushort_t* __restrict__ dst) {
    size_t i = ((size_t)blockIdx.x * 256 + threadIdx.x) * 8;
    f32x4 a = *reinterpret_cast<const f32x4*>(src + i);
    f32x4 b = *reinterpret_cast<const f32x4*>(src + i + 4);
    short8 v;
#pragma unroll
    for (int j = 0; j < 4; ++j) { v[j] = (short)f2b(a[j]); v[4 + j] = (short)f2b(b[j]); }
    *reinterpret_cast<short8*>(dst + i) = v;
}

// ---------------- transpose: dst[C][R] = src[R][C], src fp32 or bf16, dst bf16 ----------------
template <typename ST>
__global__ __launch_bounds__(64)
void transp(const ST* __restrict__ src, ushort_t* __restrict__ dst, int R, int C) {
    src += (size_t)blockIdx.z * R * C;
    dst += (size_t)blockIdx.z * R * C;
    int r0 = blockIdx.x * 64 + ((threadIdx.x >> 3) << 3);
    int c0 = blockIdx.y * 64 + ((threadIdx.x & 7) << 3);
    ushort_t v[8][8];
#pragma unroll
    for (int i = 0; i < 8; ++i) {
        const ST* p = src + (size_t)(r0 + i) * C + c0;
        if constexpr (sizeof(ST) == 4) {
            f32x4 a = *reinterpret_cast<const f32x4*>(p);
            f32x4 b = *reinterpret_cast<const f32x4*>(p + 4);
#pragma unroll
            for (int j = 0; j < 4; ++j) { v[i][j] = f2b(a[j]); v[i][4 + j] = f2b(b[j]); }
        } else {
            short8 a = *reinterpret_cast<const short8*>(p);
#pragma unroll
            for (int j = 0; j < 8; ++j) v[i][j] = (ushort_t)a[j];
        }
    }
#pragma unroll
    for (int c = 0; c < 8; ++c) {
        short8 w;
#pragma unroll
        for (int i = 0; i < 8; ++i) w[i] = (short)v[i][c];
        *reinterpret_cast<short8*>(dst + (size_t)(c0 + c) * R + r0) = w;
    }
}

// ---------------- GEMM: C[M][N] = A[M][K] @ Bt[N][K]^T + bias ----------------
// 128x128 tile, BK=64, 4 waves (2x2), swizzled LDS (XOR chunk^(row&7)).
// BHTD: scatter bf16 to [B,H,T,D]; ROPE: head-indexed rotation (+ oscale) in epilogue.
template <bool BHTD, bool ROPE>
__global__ __launch_bounds__(256)
void gemm_bt(const ushort_t* __restrict__ A, const ushort_t* __restrict__ Bt,
             const float* __restrict__ bias, void* __restrict__ Cv,
             int M, int N, int K, float oscale) {
    __shared__ __align__(16) ushort_t As[128 * 64];
    __shared__ __align__(16) ushort_t Bs[128 * 64];
    const int tid = threadIdx.x, lane = tid & 63, wid = tid >> 6;
    const int l15 = lane & 15, g = lane >> 4;
    const int wr = wid >> 1, wc = wid & 1;
    const int m0 = blockIdx.y * 128, n0 = blockIdx.x * 128;
    f32x4 acc[4][4] = {};
    for (int k0 = 0; k0 < K; k0 += 64) {
#pragma unroll
        for (int is = 0; is < 4; ++is) {
            int c = is * 256 + tid;
            int row = c >> 3, sub = c & 7;
            int ks = (sub ^ (row & 7)) << 3;   // pre-swizzled global source (involution)
            char* ldst = (char*)As + (size_t)(is * 256 + wid * 64) * 16;
            gload16(A + (size_t)(m0 + row) * K + k0 + ks, ldst);
            char* ldstB = (char*)Bs + (size_t)(is * 256 + wid * 64) * 16;
            gload16(Bt + (size_t)(n0 + row) * K + k0 + ks, ldstB);
        }
        __syncthreads();
#pragma unroll
        for (int kk = 0; kk < 2; ++kk) {
            short8 af[4], bf[4];
#pragma unroll
            for (int i = 0; i < 4; ++i) {
                int ra = wr * 64 + i * 16 + l15;
                af[i] = *reinterpret_cast<const short8*>(
                    (const char*)As + ra * 128 + (((4 * kk + g) ^ (ra & 7)) << 4));
                int rb = wc * 64 + i * 16 + l15;
                bf[i] = *reinterpret_cast<const short8*>(
                    (const char*)Bs + rb * 128 + (((4 * kk + g) ^ (rb & 7)) << 4));
            }
#pragma unroll
            for (int i = 0; i < 4; ++i)
#pragma unroll
                for (int j = 0; j < 4; ++j)
                    acc[i][j] = __builtin_amdgcn_mfma_f32_16x16x32_bf16(af[i], bf[j], acc[i][j], 0, 0, 0);
        }
        __syncthreads();
    }
#pragma unroll
    for (int j = 0; j < 4; ++j) {
        int n = n0 + wc * 64 + j * 16 + l15;
        float bj = bias[n];
        float sn = 0.f, cs = 1.f, sgn = 0.f;
        if (ROPE) {
            int d = n & 127, h = (n >> 7) & 15;
            float inv = expf(-(float)(d >> 1) * (9.210340371976184f / 64.0f)); // 10000^(-2i/128)
            sincosf((float)h * inv, &sn, &cs);
            sgn = (d & 1) ? sn : -sn;
        }
#pragma unroll
        for (int i = 0; i < 4; ++i) {
            int mbase = m0 + wr * 64 + i * 16 + g * 4;
#pragma unroll
            for (int r = 0; r < 4; ++r) {
                int m = mbase + r;
                float v = acc[i][j][r] + bj;
                if (ROPE) {
                    float p = __shfl_xor(v, 1, 64);   // d-pair partner (adjacent lane)
                    v = fmaf(p, sgn, v * cs);         // even: v*cs - p*sn ; odd: v*cs + p*sn
                    v *= oscale;                      // bake softmax scale into Q
                }
                if (BHTD) {
                    size_t addr = ((size_t)((m >> 11) * 16 + (n >> 7)) * 2048 + (m & 2047)) * 128 + (n & 127);
                    ((ushort_t*)Cv)[addr] = f2b(v);
                } else {
                    ((float*)Cv)[(size_t)m * N + n] = v;
                }
            }
        }
    }
}

// ---------------- flash attention: swapped-QK^T, in-register softmax, 8 waves ----------------
// grid (T/128, H, B); 8 waves x 16 q-rows. K[B,H,T,D], Vt[B,H,D,T]. Out [B*T][2048] bf16.
// Q is pre-scaled by (1/sqrt(128))*log2(e) -> P = exp2(s - m), no per-element multiply.
// s[nt][r] = S'[kv=16nt+4g+r][q=l15]; oacc[nt2][r] = O^T[d=16nt2+4g+r][q=l15].
__global__ __launch_bounds__(512)
void fattn(const ushort_t* __restrict__ Q, const ushort_t* __restrict__ K,
           const ushort_t* __restrict__ Vt, ushort_t* __restrict__ O) {
    __shared__ __align__(16) ushort_t Ks[2][64 * 128];   // [kv][d] swizzled
    __shared__ __align__(16) ushort_t Vs[2][128 * 64];   // [d][kv] swizzled
    const int tid = threadIdx.x, lane = tid & 63, wid = tid >> 6;
    const int l15 = lane & 15, g = lane >> 4;
    const int h = blockIdx.y, b = blockIdx.z;
    const size_t base = ((size_t)b * 16 + h) * (2048 * 128);
    const int q0 = blockIdx.x * 128 + wid * 16;
    short8 qf[4];
#pragma unroll
    for (int c = 0; c < 4; ++c)
        qf[c] = *reinterpret_cast<const short8*>(Q + base + (size_t)(q0 + l15) * 128 + c * 32 + g * 8);
    f32x4 oacc[8] = {};
    float m_r = -__builtin_inff(), l_r = 0.f;
    // bpermute byte-addrs for P redistribution (iteration-invariant)
    const int addrA = ((32 * (g & 1)) + l15) << 2;
    const int addrB = addrA + 64;
    const bool hi = (lane & 32) != 0;

    auto stage = [&](int kv0, int bsel) {
#pragma unroll
        for (int is = 0; is < 2; ++is) {
            {   // K tile [64][128]: 16 chunks/row, 1024 chunks over 512 thr x 2
                int c = is * 512 + tid;
                int row = c >> 4, sub = c & 15;
                int dsrc = (sub ^ (row & 7)) << 3;
                gload16(K + base + (size_t)(kv0 + row) * 128 + dsrc,
                        (char*)Ks[bsel] + (size_t)c * 16);
            }
            {   // Vt tile [128][64]: 8 chunks/row
                int c = is * 512 + tid;
                int row = c >> 3, sub = c & 7;
                int tsrc = (sub ^ (row & 7)) << 3;
                gload16(Vt + base + (size_t)row * 2048 + kv0 + tsrc,
                        (char*)Vs[bsel] + (size_t)c * 16);
            }
        }
    };

    stage(0, 0);
    asm volatile("s_waitcnt vmcnt(0)" ::: "memory");
    __builtin_amdgcn_s_barrier();

    for (int it = 0; it < 32; ++it) {
        const int cur = it & 1;
        if (it < 31) stage((it + 1) << 6, cur ^ 1);   // prefetch flies under compute
        // S'^T = K Q'^T (pre-scaled)
        f32x4 s[4] = {};
        __builtin_amdgcn_s_setprio(1);
#pragma unroll
        for (int nt = 0; nt < 4; ++nt) {
            int kvr = nt * 16 + l15;
#pragma unroll
            for (int c = 0; c < 4; ++c) {
                short8 kf = *reinterpret_cast<const short8*>(
                    (const char*)Ks[cur] + kvr * 256 + (((4 * c + g) ^ (kvr & 7)) << 4));
                s[nt] = __builtin_amdgcn_mfma_f32_16x16x32_bf16(kf, qf[c], s[nt], 0, 0, 0);
            }
        }
        __builtin_amdgcn_s_setprio(0);
        // row max: 15 in-reg + 2 shfl (q row spread over 4 g-lanes)
        float pm = fmaxf(fmaxf(fmaxf(s[0][0], s[0][1]), fmaxf(s[0][2], s[0][3])),
                         fmaxf(fmaxf(s[1][0], s[1][1]), fmaxf(s[1][2], s[1][3])));
        pm = fmaxf(pm, fmaxf(fmaxf(fmaxf(s[2][0], s[2][1]), fmaxf(s[2][2], s[2][3])),
                             fmaxf(fmaxf(s[3][0], s[3][1]), fmaxf(s[3][2], s[3][3]))));
        pm = fmaxf(pm, __shfl_xor(pm, 16, 64));
        pm = fmaxf(pm, __shfl_xor(pm, 32, 64));
        // defer-max (T13): rescale only when max grew past 5.0 (log2 units; p <= 32)
        if (!__all(pm <= m_r + 5.0f)) {
            float mn = fmaxf(m_r, pm);
            float fac = exp2f(m_r - mn);
            m_r = mn;
            l_r *= fac;
#pragma unroll
            for (int nt2 = 0; nt2 < 8; ++nt2)
#pragma unroll
                for (int r = 0; r < 4; ++r) oacc[nt2][r] *= fac;
        }
        // P = exp2(s - m), pack via v_cvt_pk_bf16_f32, accumulate row-sum (raw fp32)
        uint_t W[4][2];
        float rs = 0.f;
#pragma unroll
        for (int nt = 0; nt < 4; ++nt) {
            float p0 = exp2f(s[nt][0] - m_r);
            float p1 = exp2f(s[nt][1] - m_r);
            float p2 = exp2f(s[nt][2] - m_r);
            float p3 = exp2f(s[nt][3] - m_r);
            rs += (p0 + p1) + (p2 + p3);
            W[nt][0] = cvt_pk_bf16(p0, p1);
            W[nt][1] = cvt_pk_bf16(p2, p3);
        }
        rs += __shfl_xor(rs, 16, 64);
        rs += __shfl_xor(rs, 32, 64);
        l_r += rs;
        // O^T += V^T P : redistribute P words to B-fragment layout via bpermute
        __builtin_amdgcn_s_setprio(1);
#pragma unroll
        for (int ks = 0; ks < 2; ++ks) {
            uint_t xa, xb, w0, w1, w2, w3;
            xa = (uint_t)__builtin_amdgcn_ds_bpermute(addrA, (int)W[2 * ks][0]);
            xb = (uint_t)__builtin_amdgcn_ds_bpermute(addrA, (int)W[2 * ks + 1][0]);
            w0 = hi ? xb : xa;
            xa = (uint_t)__builtin_amdgcn_ds_bpermute(addrA, (int)W[2 * ks][1]);
            xb = (uint_t)__builtin_amdgcn_ds_bpermute(addrA, (int)W[2 * ks + 1][1]);
            w1 = hi ? xb : xa;
            xa = (uint_t)__builtin_amdgcn_ds_bpermute(addrB, (int)W[2 * ks][0]);
            xb = (uint_t)__builtin_amdgcn_ds_bpermute(addrB, (int)W[2 * ks + 1][0]);
            w2 = hi ? xb : xa;
            xa = (uint_t)__builtin_amdgcn_ds_bpermute(addrB, (int)W[2 * ks][1]);
            xb = (uint_t)__builtin_amdgcn_ds_bpermute(addrB, (int)W[2 * ks + 1][1]);
            w3 = hi ? xb : xa;
            uint4_t wv; wv[0] = w0; wv[1] = w1; wv[2] = w2; wv[3] = w3;
            short8 pb = __builtin_bit_cast(short8, wv);
#pragma unroll
            for (int nt2 = 0; nt2 < 8; ++nt2) {
                int dr = nt2 * 16 + l15;
                short8 vb = *reinterpret_cast<const short8*>(
                    (const char*)Vs[cur] + dr * 128 + (((ks * 4 + g) ^ (dr & 7)) << 4));
                oacc[nt2] = __builtin_amdgcn_mfma_f32_16x16x32_bf16(vb, pb, oacc[nt2], 0, 0, 0);
            }
        }
        __builtin_amdgcn_s_setprio(0);
        // end of iter: drain prefetch, then barrier
        asm volatile("s_waitcnt vmcnt(0)" ::: "memory");
        __builtin_amdgcn_s_barrier();
    }
    float inv = 1.f / l_r;
    const size_t orow = ((size_t)b * 2048 + q0 + l15) * 2048 + (size_t)h * 128;
#pragma unroll
    for (int nt2 = 0; nt2 < 8; ++nt2) {
        ushort4_t w;
#pragma unroll
        for (int r = 0; r < 4; ++r) w[r] = f2b(oacc[nt2][r] * inv);
        *reinterpret_cast<ushort4_t*>(O + orow + nt2 * 16 + g * 4) = w;
    }
}

extern "C" void kernel_launch(void* const* d_in, const int* in_sizes, int n_in,
                              void* d_out, int out_size, void* d_ws, size_t ws_size,
                              hipStream_t stream) {
    const float* x  = (const float*)d_in[0];
    const float* Wq = (const float*)d_in[1];
    const float* bq = (const float*)d_in[2];
    const float* Wk = (const float*)d_in[3];
    const float* bk = (const float*)d_in[4];
    const float* Wv = (const float*)d_in[5];
    const float* bv = (const float*)d_in[6];
    const float* Wo = (const float*)d_in[7];
    const float* bo = (const float*)d_in[8];
    float* out = (float*)d_out;
    ushort_t* ws  = (ushort_t*)d_ws;

    const size_t WSZ = 2048ull * 2048;          // weight elems (4.19M)
    const size_t TSZ = 2ull * 16 * 2048 * 128;  // tensor elems (8.39M)
    ushort_t* xb  = ws;            // bf16 x
    ushort_t* Wtq = xb + TSZ;
    ushort_t* Wtk = Wtq + WSZ;
    ushort_t* Wtv = Wtk + WSZ;
    ushort_t* Wto = Wtv + WSZ;
    ushort_t* Qb  = Wto + WSZ;
    ushort_t* Kb  = Qb + TSZ;
    ushort_t* Vtb = Kb + TSZ;
    ushort_t* Sb  = Vtb + TSZ;   // V (from gemm), then attention output

    const float QSC = 0.08838834764831845f * 1.4426950408889634f; // (1/sqrt(128))*log2(e)

    cast_bf16<<<dim3(4096), 256, 0, stream>>>(x, xb);
    transp<float><<<dim3(32, 32, 1), 64, 0, stream>>>(Wq, Wtq, 2048, 2048);
    transp<float><<<dim3(32, 32, 1), 64, 0, stream>>>(Wk, Wtk, 2048, 2048);
    transp<float><<<dim3(32, 32, 1), 64, 0, stream>>>(Wv, Wtv, 2048, 2048);
    transp<float><<<dim3(32, 32, 1), 64, 0, stream>>>(Wo, Wto, 2048, 2048);

    gemm_bt<true, true ><<<dim3(16, 32), 256, 0, stream>>>(xb, Wtq, bq, Qb, 4096, 2048, 2048, QSC);
    gemm_bt<true, true ><<<dim3(16, 32), 256, 0, stream>>>(xb, Wtk, bk, Kb, 4096, 2048, 2048, 1.0f);
    gemm_bt<true, false><<<dim3(16, 32), 256, 0, stream>>>(xb, Wtv, bv, Sb, 4096, 2048, 2048, 1.0f);

    transp<ushort_t><<<dim3(32, 2, 32), 64, 0, stream>>>(Sb, Vtb, 2048, 128);   // V -> [B,H,D,T]

    fattn<<<dim3(16, 16, 2), 512, 0, stream>>>(Qb, Kb, Vtb, Sb);

    gemm_bt<false, false><<<dim3(16, 32), 256, 0, stream>>>(Sb, Wto, bo, out, 4096, 2048, 2048, 1.0f);
}